// Round 8
// baseline (106.677 us; speedup 1.0000x reference)
//
#include <hip/hip_runtime.h>

typedef float vf4 __attribute__((ext_vector_type(4)));

// DPP move: compile-time control, bound_ctrl=1 (out-of-range lanes read 0)
template<int CTRL>
__device__ __forceinline__ float dppf(float v) {
    return __int_as_float(__builtin_amdgcn_update_dpp(
        0, __float_as_int(v), CTRL, 0xF, 0xF, true));
}

// Sum across each 4-lane quad; result valid on ALL 4 lanes.
__device__ __forceinline__ float bfly4(float v) {
    v += dppf<0xB1>(v);    // quad_perm [1,0,3,2]  (xor 1)
    v += dppf<0x4E>(v);    // quad_perm [2,3,0,1]  (xor 2)
    return v;
}

__device__ __forceinline__ float hsum4(vf4 v) { return (v.x + v.y) + (v.z + v.w); }

// Lane owns a column QUAD (cols 4*l4..4*l4+3) => 16 batches/wave, all VMEM is
// dwordx4. The full working set (64 im + 64 mc floats) must be live at once,
// forcing the compiler into an up-front burst of 24 x4-loads (high MLP).
__global__ __launch_bounds__(256, 2) void apply_area_kernel(
    const float* __restrict__ img_g,
    const float* __restrict__ mn_g,
    const float* __restrict__ mo_g,
    float* __restrict__ out,
    int B)
{
    const int lane = threadIdx.x & 63;
    const int w    = threadIdx.x >> 6;
    const int q    = lane >> 2;      // batch within wave (16 per wave)
    const int l4   = lane & 3;       // column quad: cols 4*l4..4*l4+3
    const int b    = blockIdx.x * 64 + w * 16 + q;
    if (b >= B) return;

    const vf4* im4 = reinterpret_cast<const vf4*>(img_g) + (size_t)b * 64 + l4;
    const vf4* mn4 = reinterpret_cast<const vf4*>(mn_g)  + (size_t)b * 32 + l4;
    const vf4* mo4 = reinterpret_cast<const vf4*>(mo_g)  + (size_t)b * 32 + l4;

    vf4 im[16], mc[16];
#pragma unroll
    for (int r = 0; r < 16; ++r) im[r] = im4[r * 4];
#pragma unroll
    for (int i = 0; i < 8; ++i) {    // mc row 2i = mn[i], row 2i+1 = mo[i]
        mc[2 * i]     = mn4[i * 4];
        mc[2 * i + 1] = mo4[i * 4];
    }
    asm volatile("" ::: "memory");   // keep the load burst ahead of consumption

    const vf4 z4 = {0.f, 0.f, 0.f, 0.f};

    // ---- consistency (rows in-register) ----
    vf4 cv = z4;
#pragma unroll
    for (int i = 0; i < 8; ++i) {
        vf4 mm = (i > 0) ? mc[2 * i - 1] : z4;
        vf4 mp = (i < 7) ? mc[2 * i + 3] : z4;
        vf4 g = 0.5f * (mp - mm);
        vf4 t = mc[2 * i] - 5.f * (g * g + mc[2 * i + 1]);
        cv.x += fmaxf(t.x, 0.f); cv.y += fmaxf(t.y, 0.f);
        cv.z += fmaxf(t.z, 0.f); cv.w += fmaxf(t.w, 0.f);
    }

    // ---- edge / rounding / avg_cov / per-column sums ----
    vf4 ev = z4, rv = z4, av = z4, smiv = z4, S1v = z4, S2v = z4;
    const int cb = 4 * l4;
#pragma unroll
    for (int r = 0; r < 16; ++r) {
        vf4 gi = (r == 0)  ? im[1] - im[0]
               : (r == 15) ? im[15] - im[14]
               : 0.5f * (im[r + 1] - im[r - 1]);
        vf4 gm = (r == 0)  ? mc[1] - mc[0]
               : (r == 15) ? mc[15] - mc[14]
               : 0.5f * (mc[r + 1] - mc[r - 1]);
        vf4 d = gi - gm;
        ev += 0.5f * d * d * gi;
        vf4 tw = 2.f * mc[r] - 1.f;
        rv += tw * tw;
        int abr = (r > 7) ? r - 7 : 7 - r;
        int hi = 14 - abr;
        vf4 dia;
        dia.x = (r < 15 && cb + 0 >= abr && cb + 0 <= hi) ? 1.f : 0.f;
        dia.y = (r < 15 && cb + 1 >= abr && cb + 1 <= hi) ? 1.f : 0.f;
        dia.z = (r < 15 && cb + 2 >= abr && cb + 2 <= hi) ? 1.f : 0.f;
        dia.w = (r < 15 && cb + 3 >= abr && cb + 3 <= hi) ? 1.f : 0.f;
        vf4 dd = mc[r] - dia;
        av += 0.5f * dd * dd;
        S1v += mc[r];
        S2v += mc[r] * mc[r];
        smiv += mc[r] * im[r];
    }

    // ---- 4 translations: B=Σt·im, D=Σt³·im, E=Σ(t²·im)² ----
    const float mz3 = (l4 == 3) ? 0.f : 1.f;   // quad boundary, shift-left side
    const float mz0 = (l4 == 0) ? 0.f : 1.f;   // quad boundary, shift-right side
    vf4 B0v = z4, D0v = z4, E0v = z4, B1v = z4, D1v = z4, E1v = z4;
    vf4 B2v = z4, D2v = z4, E2v = z4, B3v = z4, D3v = z4, E3v = z4;
#pragma unroll
    for (int r = 0; r < 16; ++r) {
        vf4 t0 = (r < 14) ? mc[r + 2] : z4;
        vf4 t1 = (r >= 2) ? mc[r - 2] : z4;
        vf4 m = mc[r];
        vf4 t2, t3;
        t2.x = m.z; t2.y = m.w;
        t2.z = dppf<0x101>(m.x) * mz3; t2.w = dppf<0x101>(m.y) * mz3;
        t3.x = dppf<0x111>(m.z) * mz0; t3.y = dppf<0x111>(m.w) * mz0;
        t3.z = m.x; t3.w = m.y;
#define ACC4(t, Bx, Dx, Ex) { vf4 mi_ = (t) * im[r]; Bx += mi_; \
        Dx += (t) * (t) * mi_; vf4 a_ = (t) * mi_; Ex += a_ * a_; }
        ACC4(t0, B0v, D0v, E0v)
        ACC4(t1, B1v, D1v, E1v)
        ACC4(t2, B2v, D2v, E2v)
        ACC4(t3, B3v, D3v, E3v)
#undef ACC4
    }

    // A=Σt, C=Σt² partials from per-column sums
    float S1 = hsum4(S1v), S2 = hsum4(S2v);
    float A0 = S1 - hsum4(mc[0]) - hsum4(mc[1]);
    float C0 = S2 - hsum4(mc[0] * mc[0]) - hsum4(mc[1] * mc[1]);
    float A1 = S1 - hsum4(mc[14]) - hsum4(mc[15]);
    float C1 = S2 - hsum4(mc[14] * mc[14]) - hsum4(mc[15] * mc[15]);
    float A2 = S1v.z + S1v.w + (dppf<0x101>(S1v.x) + dppf<0x101>(S1v.y)) * mz3;
    float C2 = S2v.z + S2v.w + (dppf<0x101>(S2v.x) + dppf<0x101>(S2v.y)) * mz3;
    float A3 = S1v.x + S1v.y + (dppf<0x111>(S1v.z) + dppf<0x111>(S1v.w)) * mz0;
    float C3 = S2v.x + S2v.y + (dppf<0x111>(S2v.z) + dppf<0x111>(S2v.w)) * mz0;

    // ---- 26 quad reductions (2 DPP stages each) ----
    float c_s = bfly4(hsum4(cv)), r_s = bfly4(hsum4(rv));
    float e_s = bfly4(hsum4(ev)), a_s = bfly4(hsum4(av));
    float smc = bfly4(S1),        smi = bfly4(hsum4(smiv));
    A0 = bfly4(A0); A1 = bfly4(A1); A2 = bfly4(A2); A3 = bfly4(A3);
    C0 = bfly4(C0); C1 = bfly4(C1); C2 = bfly4(C2); C3 = bfly4(C3);
    float B0 = bfly4(hsum4(B0v)), B1 = bfly4(hsum4(B1v));
    float B2 = bfly4(hsum4(B2v)), B3 = bfly4(hsum4(B3v));
    float D0 = bfly4(hsum4(D0v)), D1 = bfly4(hsum4(D1v));
    float D2 = bfly4(hsum4(D2v)), D3 = bfly4(hsum4(D3v));
    float E0 = bfly4(hsum4(E0v)), E1 = bfly4(hsum4(E1v));
    float E2 = bfly4(hsum4(E2v)), E3 = bfly4(hsum4(E3v));

    // ---- stores (NT dwordx4) ----
    const float scale = smi / smc;
    vf4* mco = reinterpret_cast<vf4*>(out) + (size_t)b * 64 + l4;
    vf4* oio = reinterpret_cast<vf4*>(out) + (size_t)B * 64 + (size_t)b * 64 + l4;
#pragma unroll
    for (int r = 0; r < 16; ++r) {
        __builtin_nontemporal_store(mc[r], mco + r * 4);
        __builtin_nontemporal_store(mc[r] * scale, oio + r * 4);
    }

    // ---- scalar epilogue: 4 coalesced streams (one per l4) + 1 extra ----
    float m0 = B0 / A0, m1 = B1 / A1, m2 = B2 / A2, m3 = B3 / A3;
    float v0 = (E0 - 2.f * m0 * D0 + m0 * m0 * C0) / A0;
    float v1 = (E1 - 2.f * m1 * D1 + m1 * m1 * C1) / A1;
    float v2 = (E2 - 2.f * m2 * D2 + m2 * m2 * C2) / A2;
    float v3 = (E3 - 2.f * m3 * D3 + m3 * m3 * C3) / A3;
    float fm = 0.25f * (m0 + m1 + m2 + m3);
    float dm0 = m0 - fm, dm1 = m1 - fm, dm2 = m2 - fm, dm3 = m3 - fm;
    float vm = 0.25f * (dm0 * dm0 + dm1 * dm1 + dm2 * dm2 + dm3 * dm3);
    float fv = 0.25f * (v0 + v1 + v2 + v3);
    float dv0 = v0 - fv, dv1 = v1 - fv, dv2 = v2 - fv, dv3 = v3 - fv;
    float vv = 0.25f * (dv0 * dv0 + dv1 * dv1 + dv2 * dv2 + dv3 * dv3);

    float sv = (l4 == 0) ? c_s * (1.f / 128.f)
             : (l4 == 1) ? -r_s * (1.f / 256.f)
             : (l4 == 2) ? 0.5f * (vm + vv)
             :             e_s * (1.f / 256.f);
    float* s = out + (size_t)B * 512;
    __builtin_nontemporal_store(sv, s + (size_t)l4 * B + b);
    if (l4 == 0)
        __builtin_nontemporal_store(a_s * (1.f / 256.f), s + 4 * (size_t)B + b);
}

extern "C" void kernel_launch(void* const* d_in, const int* in_sizes, int n_in,
                              void* d_out, int out_size, void* d_ws, size_t ws_size,
                              hipStream_t stream) {
    const float* img = (const float*)d_in[0];
    const float* mn  = (const float*)d_in[1];
    const float* mo  = (const float*)d_in[2];
    float* out = (float*)d_out;
    const int B = in_sizes[0] / 256;
    const int blocks = (B + 63) / 64;   // 64 batches per 256-thread block
    apply_area_kernel<<<blocks, 256, 0, stream>>>(img, mn, mo, out, B);
}